// Round 11
// baseline (17676.584 us; speedup 1.0000x reference)
//
#include <hip/hip_runtime.h>
#include <math.h>

#define BATCH 64
#define HH 256
#define WW 256
#define HW 65536            // 256*256 pixels per image
#define NBINS 50
#define SENT_P 0x7FFFFFFF   // background marker (never produced by area encoding)

__device__ __forceinline__ int aload(const int* p) {
    return __hip_atomic_load(p, __ATOMIC_RELAXED, __HIP_MEMORY_SCOPE_AGENT);
}
__device__ __forceinline__ void astore(int* p, int v) {
    __hip_atomic_store(p, v, __ATOMIC_RELAXED, __HIP_MEMORY_SCOPE_AGENT);
}

// One block per image; all phases block-local.
// R11: R6 baseline (first-occurrence argmaxes, f32 [0,1)/50 trunc binning,
// 4-conn fixpoint CC) with ONE change: the fg compare uses a FLOAT64
// threshold ind_sec/50.0 (np transcription yields int64/int -> f64, and
// `a > thr` promotes a to f64). Pixels exactly at f32(k/50) where
// f32(k/50) > k/50 (e.g. 0.54) are fg in the np ref but were bg under the
// f32 compare -- the exact 0.98828125-0.5390625 = 0.44921875 signature.
__global__ __launch_bounds__(1024)
void k_all(const float* __restrict__ att, float* out) {
    const int b = blockIdx.x;
    const int t = threadIdx.x;
    const float* A = att + (size_t)b * HW;
    int* L = (int*)out + (size_t)b * HW;

    __shared__ int hist[NBINS];
    __shared__ double s_thr;
    __shared__ int s_changed;

    // ---- Phase A: histogram (f32 trunc binning, matches (flat*50).astype(i32)) ----
    for (int i = t; i < NBINS; i += 1024) hist[i] = 0;
    if (t == 0) s_changed = 0;
    __syncthreads();
    const float4* src4 = (const float4*)A;
    for (int i = t; i < HW / 4; i += 1024) {
        float4 v = src4[i];
        atomicAdd(&hist[min((int)(v.x * 50.0f), 49)], 1);
        atomicAdd(&hist[min((int)(v.y * 50.0f), 49)], 1);
        atomicAdd(&hist[min((int)(v.z * 50.0f), 49)], 1);
        atomicAdd(&hist[min((int)(v.w * 50.0f), 49)], 1);
    }
    __syncthreads();
    if (t == 0) {
        int ind_max = 0, bv = hist[0];
        for (int j = 1; j < NBINS; ++j)
            if (hist[j] > bv) { bv = hist[j]; ind_max = j; }   // first-occurrence argmax
        int ind_sec = 0, bv2 = -1;                             // masked[0] == -1 always
        for (int j = 1; j < NBINS; ++j) {
            int v = (j > ind_max) ? hist[j] : -1;
            if (v > bv2) { bv2 = v; ind_sec = j; }             // first-occurrence (R10 confirmed)
        }
        s_thr = (double)ind_sec / 50.0;                        // FLOAT64 threshold
    }
    __syncthreads();
    const double tv = s_thr;

    // ---- Phase B: init labels (f64 compare: x promoted to double) ----
    for (int i = t; i < HW / 4; i += 1024) {
        float4 v = src4[i];
        int l = i * 4;
        astore(L + l + 0, ((double)v.x > tv) ? (l + 0) : SENT_P);
        astore(L + l + 1, ((double)v.y > tv) ? (l + 1) : SENT_P);
        astore(L + l + 2, ((double)v.z > tv) ? (l + 2) : SENT_P);
        astore(L + l + 3, ((double)v.w > tv) ? (l + 3) : SENT_P);
    }
    __syncthreads();

    // ---- Phase C: min-label propagation to fixpoint (4-connectivity) ----
    for (;;) {
        int changed = 0;
        for (int p = t; p < HW; p += 1024) {
            int v = aload(L + p);
            if (v == SENT_P) continue;
            int m = v;
            int col = p & (WW - 1), row = p >> 8;
            if (col > 0)      m = min(m, aload(L + p - 1));
            if (col < WW - 1) m = min(m, aload(L + p + 1));
            if (row > 0)      m = min(m, aload(L + p - WW));
            if (row < HH - 1) m = min(m, aload(L + p + WW));
            m = min(m, aload(L + m));      // shortcut: label-of-label (doubling)
            if (m < v) { astore(L + p, m); changed = 1; }
        }
        if (changed) s_changed = 1;
        __syncthreads();                   // all updates + flag sets done
        int ch = s_changed;
        __syncthreads();                   // all reads of flag done
        if (!ch) break;
        if (t == 0) s_changed = 0;
        __syncthreads();                   // reset visible before next sweep
    }

    // ---- Phase D: count (non-root members add 1<<16 into root slot) ----
    for (int p = t; p < HW; p += 1024) {
        int v = aload(L + p);
        if (v == SENT_P) continue;
        int lo = v & 0xFFFF;
        if (lo != p) atomicAdd((unsigned int*)(L + lo), 0x10000u);
    }
    __syncthreads();

    // ---- Phase E: distribute encoded root word to members ----
    for (int p = t; p < HW; p += 1024) {
        int v = aload(L + p);
        if (v == SENT_P) continue;
        int lo = v & 0xFFFF;
        if (lo != p) astore(L + p, aload(L + lo));  // roots read-only here
    }
    __syncthreads();

    // ---- Phase F: finalize ----
    for (int p = t; p < HW; p += 1024) {
        float x = A[p];
        unsigned v = (unsigned)aload(L + p);        // L aliases out; read first
        float y = x;
        if (v != (unsigned)SENT_P) {
            float a = (float)((v >> 16) + 1u);      // component area
            y = powf(x, 1.0f / sqrtf(a));
        }
        out[(size_t)b * HW + p] = y;
    }
}

extern "C" void kernel_launch(void* const* d_in, const int* in_sizes, int n_in,
                              void* d_out, int out_size, void* d_ws, size_t ws_size,
                              hipStream_t stream) {
    const float* att = (const float*)d_in[0];
    float* out = (float*)d_out;
    (void)d_ws; (void)ws_size; (void)in_sizes; (void)n_in; (void)out_size;

    k_all<<<BATCH, 1024, 0, stream>>>(att, out);
}

// Round 12
// 4377.763 us; speedup vs baseline: 4.0378x; 4.0378x over previous
//
#include <hip/hip_runtime.h>
#include <math.h>

#define BATCH 64
#define HH 256
#define WW 256
#define HW 65536            // 256*256 pixels per image
#define NPIX (BATCH * HW)   // 4194304
#define NBINS 50
#define SENT_P 0x7FFFFFFF   // background marker (never produced by area encoding)

// ws layout: int histg[64][64] (16 KB), then double thr[64] (512 B)

__device__ __forceinline__ int aload(const int* p) {
    return __hip_atomic_load(p, __ATOMIC_RELAXED, __HIP_MEMORY_SCOPE_AGENT);
}
__device__ __forceinline__ void astore(int* p, int v) {
    __hip_atomic_store(p, v, __ATOMIC_RELAXED, __HIP_MEMORY_SCOPE_AGENT);
}

// ---- K0: clear per-image histograms ----
__global__ void k_clear(int* __restrict__ histg) {
    int i = blockIdx.x * blockDim.x + threadIdx.x;
    if (i < BATCH * 64) histg[i] = 0;
}

// ---- K1: histogram, 8 blocks per image (f32 trunc binning = jnp port) ----
__global__ void k_hist(const float* __restrict__ att, int* __restrict__ histg) {
    __shared__ int h[NBINS];
    const int b = blockIdx.y, c = blockIdx.x, t = threadIdx.x;
    if (t < NBINS) h[t] = 0;
    __syncthreads();
    const float4* src = (const float4*)(att + (size_t)b * HW) + c * 2048;
    for (int i = t; i < 2048; i += 256) {
        float4 v = src[i];
        atomicAdd(&h[min((int)(v.x * 50.0f), 49)], 1);
        atomicAdd(&h[min((int)(v.y * 50.0f), 49)], 1);
        atomicAdd(&h[min((int)(v.z * 50.0f), 49)], 1);
        atomicAdd(&h[min((int)(v.w * 50.0f), 49)], 1);
    }
    __syncthreads();
    if (t < NBINS) atomicAdd(&histg[b * 64 + t], h[t]);
}

// ---- K2: per-image threshold (FLOAT64 — the R11-proven semantics) ----
__global__ void k_thr(const int* __restrict__ histg, double* __restrict__ thr) {
    int b = threadIdx.x;
    if (b >= BATCH) return;
    const int* h = histg + b * 64;
    int ind_max = 0, bv = h[0];
    for (int j = 1; j < NBINS; ++j)
        if (h[j] > bv) { bv = h[j]; ind_max = j; }     // first-occurrence argmax
    int ind_sec = 0, bv2 = -1;                          // masked[0] == -1 always
    for (int j = 1; j < NBINS; ++j) {
        int v = (j > ind_max) ? h[j] : -1;
        if (v > bv2) { bv2 = v; ind_sec = j; }          // first-occurrence
    }
    thr[b] = (double)ind_sec / 50.0;
}

// ---- K3: init labels (f64 compare) ----
__global__ void k_init(const float* __restrict__ att, const double* __restrict__ thr,
                       int* __restrict__ parent) {
    int g = blockIdx.x * blockDim.x + threadIdx.x;   // one thread per 4 px
    int base = g * 4;
    if (base >= NPIX) return;
    double tv = thr[base >> 16];
    float4 v = ((const float4*)att)[g];
    int l = base & (HW - 1);
    int4 p;
    p.x = ((double)v.x > tv) ? (l + 0) : SENT_P;
    p.y = ((double)v.y > tv) ? (l + 1) : SENT_P;
    p.z = ((double)v.z > tv) ? (l + 2) : SENT_P;
    p.w = ((double)v.w > tv) ? (l + 3) : SENT_P;
    ((int4*)parent)[g] = p;
}

// ---- union-find ----
__device__ __forceinline__ int findroot(const int* P, int x) {
    int p = aload(P + x);
    while (p != x) { x = p; p = aload(P + x); }
    return x;
}
__device__ __forceinline__ void unite(int* P, int a, int b) {
    int ra = findroot(P, a);
    int rb = findroot(P, b);
    while (ra != rb) {
        int lo = min(ra, rb), hi = max(ra, rb);
        int old = atomicMin(&P[hi], lo);
        if (old == hi) return;       // linked
        ra = findroot(P, lo);        // hi already linked elsewhere; retry
        rb = findroot(P, old);
    }
}

// ---- K4: merge (union right + down) ----
__global__ void k_merge(int* parent) {
    int g = blockIdx.x * blockDim.x + threadIdx.x;
    if (g >= NPIX) return;
    int l = g & (HW - 1);
    int* P = parent + (g & ~(HW - 1));
    if (aload(P + l) == SENT_P) return;
    int col = l & (WW - 1), row = l >> 8;
    if (col + 1 < WW && aload(P + l + 1) != SENT_P)  unite(P, l, l + 1);
    if (row + 1 < HH && aload(P + l + WW) != SENT_P) unite(P, l, l + WW);
}

// ---- K5: flatten + count fused ----
// Masked traversal (&0xFFFF) is exact: only TRUE ROOT slots ever carry count
// bits (their low 16 bits remain the root index), mid-chain slots stay pure.
__global__ void k_flatcount(int* parent) {
    int g = blockIdx.x * blockDim.x + threadIdx.x;
    if (g >= NPIX) return;
    int l = g & (HW - 1);
    int* P = parent + (g & ~(HW - 1));
    int v = aload(P + l);
    if (v == SENT_P) return;
    int x = l, p = v & 0xFFFF;
    while (p != x) { x = p; p = aload(P + x) & 0xFFFF; }
    if (x != l) {
        astore(P + l, x);                                   // path compress
        atomicAdd((unsigned int*)(P + x), 0x10000u);        // count me at root
    }
}

// ---- K6: distribute encoded root word to members ----
// Required as its own pass: parent aliases d_out, so k_final may not gather
// root slots (they'd race with float output overwrites).
__global__ void k_dist(int* parent) {
    int g = blockIdx.x * blockDim.x + threadIdx.x;
    if (g >= NPIX) return;
    int v = aload(parent + g);
    if (v == SENT_P) return;
    int l = g & (HW - 1);
    int lo = v & 0xFFFF;
    if (lo != l)   // members only; root slots read-only here -> race-free
        astore(parent + g, aload(parent + (g & ~(HW - 1)) + lo));
}

// ---- K7: finalize (element-local, vectorized) ----
__global__ void k_final(const float* __restrict__ att, const int* parent, float* out) {
    int g = blockIdx.x * blockDim.x + threadIdx.x;   // one thread per 4 px
    int base = g * 4;
    if (base >= NPIX) return;
    float4 v = ((const float4*)att)[g];
    int4 pv = ((const int4*)parent)[g];              // own slots only
    float4 y;
    {
        unsigned p = (unsigned)pv.x; float x = v.x;
        y.x = (p != (unsigned)SENT_P) ? powf(x, 1.0f / sqrtf((float)((p >> 16) + 1u))) : x;
    }
    {
        unsigned p = (unsigned)pv.y; float x = v.y;
        y.y = (p != (unsigned)SENT_P) ? powf(x, 1.0f / sqrtf((float)((p >> 16) + 1u))) : x;
    }
    {
        unsigned p = (unsigned)pv.z; float x = v.z;
        y.z = (p != (unsigned)SENT_P) ? powf(x, 1.0f / sqrtf((float)((p >> 16) + 1u))) : x;
    }
    {
        unsigned p = (unsigned)pv.w; float x = v.w;
        y.w = (p != (unsigned)SENT_P) ? powf(x, 1.0f / sqrtf((float)((p >> 16) + 1u))) : x;
    }
    ((float4*)out)[g] = y;
}

extern "C" void kernel_launch(void* const* d_in, const int* in_sizes, int n_in,
                              void* d_out, int out_size, void* d_ws, size_t ws_size,
                              hipStream_t stream) {
    const float* att = (const float*)d_in[0];
    float* out = (float*)d_out;
    int* parent = (int*)d_out;                 // labels/areas live in d_out during CC
    int* histg = (int*)d_ws;                   // 64*64 ints
    double* thr = (double*)((char*)d_ws + BATCH * 64 * sizeof(int));
    (void)in_sizes; (void)n_in; (void)out_size; (void)ws_size;

    k_clear<<<4, 1024, 0, stream>>>(histg);
    k_hist<<<dim3(8, BATCH), 256, 0, stream>>>(att, histg);
    k_thr<<<1, 64, 0, stream>>>(histg, thr);
    k_init<<<NPIX / (256 * 4), 256, 0, stream>>>(att, thr, parent);
    k_merge<<<NPIX / 256, 256, 0, stream>>>(parent);
    k_flatcount<<<NPIX / 256, 256, 0, stream>>>(parent);
    k_dist<<<NPIX / 256, 256, 0, stream>>>(parent);
    k_final<<<NPIX / (256 * 4), 256, 0, stream>>>(att, parent, out);
}

// Round 14
// 803.300 us; speedup vs baseline: 22.0050x; 5.4497x over previous
//
#include <hip/hip_runtime.h>
#include <math.h>

#define BATCH 64
#define HH 256
#define WW 256
#define HW 65536            // 256*256 pixels per image
#define NPIX (BATCH * HW)   // 4194304
#define NBINS 50
#define SENT_P 0x7FFFFFFF   // background marker (never produced by area encoding)

// ws layout: int histg[64][64] (16 KB), then double thr[64] (512 B)

__device__ __forceinline__ int aload(const int* p) {
    return __hip_atomic_load(p, __ATOMIC_RELAXED, __HIP_MEMORY_SCOPE_AGENT);
}
__device__ __forceinline__ void astore(int* p, int v) {
    __hip_atomic_store(p, v, __ATOMIC_RELAXED, __HIP_MEMORY_SCOPE_AGENT);
}

// ---- K0: clear per-image histograms ----
__global__ void k_clear(int* __restrict__ histg) {
    int i = blockIdx.x * blockDim.x + threadIdx.x;
    if (i < BATCH * 64) histg[i] = 0;
}

// ---- K1: histogram, 8 blocks per image (f32 trunc binning = jnp port) ----
__global__ void k_hist(const float* __restrict__ att, int* __restrict__ histg) {
    __shared__ int h[NBINS];
    const int b = blockIdx.y, c = blockIdx.x, t = threadIdx.x;
    if (t < NBINS) h[t] = 0;
    __syncthreads();
    const float4* src = (const float4*)(att + (size_t)b * HW) + c * 2048;
    for (int i = t; i < 2048; i += 256) {
        float4 v = src[i];
        atomicAdd(&h[min((int)(v.x * 50.0f), 49)], 1);
        atomicAdd(&h[min((int)(v.y * 50.0f), 49)], 1);
        atomicAdd(&h[min((int)(v.z * 50.0f), 49)], 1);
        atomicAdd(&h[min((int)(v.w * 50.0f), 49)], 1);
    }
    __syncthreads();
    if (t < NBINS) atomicAdd(&histg[b * 64 + t], h[t]);
}

// ---- K2: per-image threshold (FLOAT64 — the R11-proven semantics) ----
__global__ void k_thr(const int* __restrict__ histg, double* __restrict__ thr) {
    int b = threadIdx.x;
    if (b >= BATCH) return;
    const int* h = histg + b * 64;
    int ind_max = 0, bv = h[0];
    for (int j = 1; j < NBINS; ++j)
        if (h[j] > bv) { bv = h[j]; ind_max = j; }     // first-occurrence argmax
    int ind_sec = 0, bv2 = -1;                          // masked[0] == -1 always
    for (int j = 1; j < NBINS; ++j) {
        int v = (j > ind_max) ? h[j] : -1;
        if (v > bv2) { bv2 = v; ind_sec = j; }          // first-occurrence
    }
    thr[b] = (double)ind_sec / 50.0;
}

// ---- K3: init labels (f64 compare) ----
__global__ void k_init(const float* __restrict__ att, const double* __restrict__ thr,
                       int* __restrict__ parent) {
    int g = blockIdx.x * blockDim.x + threadIdx.x;   // one thread per 4 px
    int base = g * 4;
    if (base >= NPIX) return;
    double tv = thr[base >> 16];
    float4 v = ((const float4*)att)[g];
    int l = base & (HW - 1);
    int4 p;
    p.x = ((double)v.x > tv) ? (l + 0) : SENT_P;
    p.y = ((double)v.y > tv) ? (l + 1) : SENT_P;
    p.z = ((double)v.z > tv) ? (l + 2) : SENT_P;
    p.w = ((double)v.w > tv) ? (l + 3) : SENT_P;
    ((int4*)parent)[g] = p;
}

// ---- union-find with path halving ----
__device__ __forceinline__ int findroot_h(int* P, int x) {
    int p = aload(P + x);
    while (p != x) {
        int gp = aload(P + p);
        astore(P + x, gp);    // halving; stores a valid smaller ancestor
        x = gp;
        p = aload(P + x);
    }
    return x;
}
__device__ __forceinline__ void unite(int* P, int a, int b) {
    int ra = findroot_h(P, a);
    int rb = findroot_h(P, b);
    while (ra != rb) {
        int lo = min(ra, rb), hi = max(ra, rb);
        int old = atomicMin(&P[hi], lo);
        if (old == hi) return;       // linked
        ra = findroot_h(P, lo);      // hi already linked elsewhere; retry
        rb = findroot_h(P, old);
    }
}

// ---- K4: merge (union right + down) ----
__global__ void k_merge(int* parent) {
    int g = blockIdx.x * blockDim.x + threadIdx.x;
    if (g >= NPIX) return;
    int l = g & (HW - 1);
    int* P = parent + (g & ~(HW - 1));
    if (aload(P + l) == SENT_P) return;
    int col = l & (WW - 1), row = l >> 8;
    if (col + 1 < WW && aload(P + l + 1) != SENT_P)  unite(P, l, l + 1);
    if (row + 1 < HH && aload(P + l + WW) != SENT_P) unite(P, l, l + WW);
}

// ---- K5: flatten + count fused (halving walk + wave-aggregated atomics) ----
// Masked (&0xFFFF) walks: only TRUE ROOT slots carry count bits; member slots
// always hold pure strictly-smaller ancestor indices, so walks strictly
// decrease and terminate at the component root. Racing halving stores may
// leave slots pointing at INTERMEDIATE ancestors (k_dist walks, so fine).
__global__ void k_flatcount(int* parent) {
    int g = blockIdx.x * blockDim.x + threadIdx.x;
    int l = g & (HW - 1);
    int* P = parent + (g & ~(HW - 1));
    int v = (g < NPIX) ? aload(P + l) : SENT_P;
    bool fg = (v != SENT_P);
    int root = l;
    if (fg) {
        int x = l, p = v & 0xFFFF;
        while (p != x) {
            int gp = aload(P + p) & 0xFFFF;
            astore(P + x, gp);          // halving; non-root slot, pure value
            x = gp;
            p = aload(P + x) & 0xFFFF;
        }
        root = x;
        if (root != l) astore(P + l, root);   // own-slot compress (best effort)
    }
    // wave-aggregated count: one atomicAdd per distinct root per wave
    bool need = fg && (root != l);
    unsigned long long active = __ballot(need);
    const int lane = (int)(threadIdx.x & 63);
    while (active) {
        int leader = (int)__builtin_ctzll(active);
        int lroot = __shfl(root, leader);
        bool mine = need && (root == lroot);
        unsigned long long grp = __ballot(mine);
        if (lane == leader)
            atomicAdd((unsigned int*)(P + lroot), (unsigned int)__popcll(grp) << 16);
        active &= ~grp;
        need = need && !mine;
    }
}

// ---- K6: distribute — WALK to root, copy full encoded word ----
// R13 bug: single-level gather assumed full compression, but racing halving
// stores can leave slots at intermediate ancestors -> copied a rootless word
// (count=0) -> area=1 identity pixels. The masked walk is robust: encoded
// words' low 16 bits ARE the root index, so reading a concurrently-written
// member slot just fast-forwards; root slots are never written here.
__global__ void k_dist(int* parent) {
    int g = blockIdx.x * blockDim.x + threadIdx.x;
    if (g >= NPIX) return;
    int v = aload(parent + g);
    if (v == SENT_P) return;
    int l = g & (HW - 1);
    int* P = parent + (g & ~(HW - 1));
    int x = v & 0xFFFF;
    if (x == l) return;                  // root: own slot already the word
    int w = aload(P + x);
    while ((w & 0xFFFF) != x) { x = w & 0xFFFF; w = aload(P + x); }
    astore(parent + g, w);               // full root word: root | count<<16
}

// ---- K7: finalize (element-local, vectorized) ----
__global__ void k_final(const float* __restrict__ att, const int* parent, float* out) {
    int g = blockIdx.x * blockDim.x + threadIdx.x;   // one thread per 4 px
    int base = g * 4;
    if (base >= NPIX) return;
    float4 v = ((const float4*)att)[g];
    int4 pv = ((const int4*)parent)[g];              // own slots only
    float4 y;
    {
        unsigned p = (unsigned)pv.x; float x = v.x;
        y.x = (p != (unsigned)SENT_P) ? powf(x, 1.0f / sqrtf((float)((p >> 16) + 1u))) : x;
    }
    {
        unsigned p = (unsigned)pv.y; float x = v.y;
        y.y = (p != (unsigned)SENT_P) ? powf(x, 1.0f / sqrtf((float)((p >> 16) + 1u))) : x;
    }
    {
        unsigned p = (unsigned)pv.z; float x = v.z;
        y.z = (p != (unsigned)SENT_P) ? powf(x, 1.0f / sqrtf((float)((p >> 16) + 1u))) : x;
    }
    {
        unsigned p = (unsigned)pv.w; float x = v.w;
        y.w = (p != (unsigned)SENT_P) ? powf(x, 1.0f / sqrtf((float)((p >> 16) + 1u))) : x;
    }
    ((float4*)out)[g] = y;
}

extern "C" void kernel_launch(void* const* d_in, const int* in_sizes, int n_in,
                              void* d_out, int out_size, void* d_ws, size_t ws_size,
                              hipStream_t stream) {
    const float* att = (const float*)d_in[0];
    float* out = (float*)d_out;
    int* parent = (int*)d_out;                 // labels/areas live in d_out during CC
    int* histg = (int*)d_ws;                   // 64*64 ints
    double* thr = (double*)((char*)d_ws + BATCH * 64 * sizeof(int));
    (void)in_sizes; (void)n_in; (void)out_size; (void)ws_size;

    k_clear<<<4, 1024, 0, stream>>>(histg);
    k_hist<<<dim3(8, BATCH), 256, 0, stream>>>(att, histg);
    k_thr<<<1, 64, 0, stream>>>(histg, thr);
    k_init<<<NPIX / (256 * 4), 256, 0, stream>>>(att, thr, parent);
    k_merge<<<NPIX / 256, 256, 0, stream>>>(parent);
    k_flatcount<<<NPIX / 256, 256, 0, stream>>>(parent);
    k_dist<<<NPIX / 256, 256, 0, stream>>>(parent);
    k_final<<<NPIX / (256 * 4), 256, 0, stream>>>(att, parent, out);
}

// Round 15
// 321.561 us; speedup vs baseline: 54.9712x; 2.4981x over previous
//
#include <hip/hip_runtime.h>
#include <math.h>

#define BATCH 64
#define HH 256
#define WW 256
#define HW 65536            // 256*256 pixels per image
#define NPIX (BATCH * HW)   // 4194304
#define NBINS 50
#define SENT_P 0x7FFFFFFF   // background marker (never produced by area encoding)

#define TW 64               // tile width
#define TH 64               // tile height
#define TN (TW * TH)        // 4096 px per tile
#define TILES_X (WW / TW)   // 4
#define TILES_Y (HH / TH)   // 4
#define TILES_PER_IMG (TILES_X * TILES_Y)  // 16

// ws layout: int histg[64][64] (16 KB), then double thr[64] (512 B)

__device__ __forceinline__ int aload(const int* p) {
    return __hip_atomic_load(p, __ATOMIC_RELAXED, __HIP_MEMORY_SCOPE_AGENT);
}
__device__ __forceinline__ void astore(int* p, int v) {
    __hip_atomic_store(p, v, __ATOMIC_RELAXED, __HIP_MEMORY_SCOPE_AGENT);
}

// ---- K0: clear per-image histograms ----
__global__ void k_clear(int* __restrict__ histg) {
    int i = blockIdx.x * blockDim.x + threadIdx.x;
    if (i < BATCH * 64) histg[i] = 0;
}

// ---- K1: histogram, 8 blocks per image (f32 trunc binning = jnp port) ----
__global__ void k_hist(const float* __restrict__ att, int* __restrict__ histg) {
    __shared__ int h[NBINS];
    const int b = blockIdx.y, c = blockIdx.x, t = threadIdx.x;
    if (t < NBINS) h[t] = 0;
    __syncthreads();
    const float4* src = (const float4*)(att + (size_t)b * HW) + c * 2048;
    for (int i = t; i < 2048; i += 256) {
        float4 v = src[i];
        atomicAdd(&h[min((int)(v.x * 50.0f), 49)], 1);
        atomicAdd(&h[min((int)(v.y * 50.0f), 49)], 1);
        atomicAdd(&h[min((int)(v.z * 50.0f), 49)], 1);
        atomicAdd(&h[min((int)(v.w * 50.0f), 49)], 1);
    }
    __syncthreads();
    if (t < NBINS) atomicAdd(&histg[b * 64 + t], h[t]);
}

// ---- K2: per-image threshold (FLOAT64 — the R11-proven semantics) ----
__global__ void k_thr(const int* __restrict__ histg, double* __restrict__ thr) {
    int b = threadIdx.x;
    if (b >= BATCH) return;
    const int* h = histg + b * 64;
    int ind_max = 0, bv = h[0];
    for (int j = 1; j < NBINS; ++j)
        if (h[j] > bv) { bv = h[j]; ind_max = j; }     // first-occurrence argmax
    int ind_sec = 0, bv2 = -1;                          // masked[0] == -1 always
    for (int j = 1; j < NBINS; ++j) {
        int v = (j > ind_max) ? h[j] : -1;
        if (v > bv2) { bv2 = v; ind_sec = j; }          // first-occurrence
    }
    thr[b] = (double)ind_sec / 50.0;
}

// ---- LDS union-find (block-local) ----
__device__ __forceinline__ int lfind(int* lp, int x) {
    int p = lp[x];
    while (p != x) {
        int gp = lp[p];
        lp[x] = gp;           // halving
        x = gp; p = lp[x];
    }
    return x;
}
__device__ __forceinline__ void lunite(int* lp, int a, int b) {
    int ra = lfind(lp, a), rb = lfind(lp, b);
    while (ra != rb) {
        int lo = min(ra, rb), hi = max(ra, rb);
        int old = atomicMin(&lp[hi], lo);
        if (old == hi) return;
        ra = lfind(lp, lo); rb = lfind(lp, old);
    }
}

// ---- K3: fused init + tile-local CC ----
// One block per 64x64 tile: fg from att/thr, union-find entirely in LDS,
// then global parent[px] = image-index of the tile-local root (depth<=1).
__global__ __launch_bounds__(256)
void k_init_cc(const float* __restrict__ att, const double* __restrict__ thr,
               int* parent) {
    __shared__ int lp[TN];
    const int tile = blockIdx.x;            // 0..15
    const int b = blockIdx.y;
    const int t = threadIdx.x;
    const int tr0 = (tile / TILES_X) * TH;  // tile row origin in image
    const int tc0 = (tile % TILES_X) * TW;  // tile col origin
    const double tv = thr[b];
    const float* A = att + (size_t)b * HW;

    // load + fg init: thread t covers 4 px along a row via float4
    // i in [0,1024): r = i>>4, c4 = (i&15)*4
    for (int i = t; i < TN / 4; i += 256) {
        int r = i >> 4, c4 = (i & 15) * 4;
        float4 v = *(const float4*)(A + (tr0 + r) * WW + tc0 + c4);
        int l = r * TW + c4;
        lp[l + 0] = ((double)v.x > tv) ? (l + 0) : SENT_P;
        lp[l + 1] = ((double)v.y > tv) ? (l + 1) : SENT_P;
        lp[l + 2] = ((double)v.z > tv) ? (l + 2) : SENT_P;
        lp[l + 3] = ((double)v.w > tv) ? (l + 3) : SENT_P;
    }
    __syncthreads();

    // local unions: right + down edges inside the tile
    for (int i = t; i < TN; i += 256) {
        if (lp[i] == SENT_P) continue;
        int r = i >> 6, c = i & (TW - 1);
        if (c + 1 < TW && lp[i + 1] != SENT_P)  lunite(lp, i, i + 1);
        if (r + 1 < TH && lp[i + TW] != SENT_P) lunite(lp, i, i + TW);
    }
    __syncthreads();

    // write global parent: member -> image-index of local root
    int* P = parent + (size_t)b * HW;
    for (int i = t; i < TN; i += 256) {
        int r = i >> 6, c = i & (TW - 1);
        int gidx = (tr0 + r) * WW + tc0 + c;
        int w;
        if (lp[i] == SENT_P) w = SENT_P;
        else {
            int root = lfind(lp, i);
            w = (tr0 + (root >> 6)) * WW + tc0 + (root & (TW - 1));
        }
        astore(P + gidx, w);
    }
}

// ---- global union-find with path halving ----
__device__ __forceinline__ int findroot_h(int* P, int x) {
    int p = aload(P + x);
    while (p != x) {
        int gp = aload(P + p);
        astore(P + x, gp);
        x = gp; p = aload(P + x);
    }
    return x;
}
__device__ __forceinline__ void unite(int* P, int a, int b) {
    int ra = findroot_h(P, a);
    int rb = findroot_h(P, b);
    while (ra != rb) {
        int lo = min(ra, rb), hi = max(ra, rb);
        int old = atomicMin(&P[hi], lo);
        if (old == hi) return;
        ra = findroot_h(P, lo);
        rb = findroot_h(P, old);
    }
}

// ---- K4: boundary merge — only cross-tile edges (1536 per image) ----
__global__ void k_bmerge(int* parent) {
    int g = blockIdx.x * blockDim.x + threadIdx.x;
    if (g >= BATCH * 1536) return;
    int b = g / 1536, e = g % 1536;
    int* P = parent + (size_t)b * HW;
    int l, m;
    if (e < 768) {          // vertical edges: col in {63,127,191} -> col+1
        int k = e / 256, row = e & 255;
        int col = TW - 1 + TW * k;
        l = row * WW + col; m = l + 1;
    } else {                // horizontal edges: row in {63,127,191} -> row+1
        int e2 = e - 768;
        int k = e2 / 256, col = e2 & 255;
        int row = TH - 1 + TH * k;
        l = row * WW + col; m = l + WW;
    }
    if (aload(P + l) != SENT_P && aload(P + m) != SENT_P) unite(P, l, m);
}

// ---- K5: flatten + count (halving walk + wave-aggregated atomics) ----
// Masked (&0xFFFF) walks: only TRUE ROOT slots carry count bits.
__global__ void k_flatcount(int* parent) {
    int g = blockIdx.x * blockDim.x + threadIdx.x;
    int l = g & (HW - 1);
    int* P = parent + (g & ~(HW - 1));
    int v = (g < NPIX) ? aload(P + l) : SENT_P;
    bool fg = (v != SENT_P);
    int root = l;
    if (fg) {
        int x = l, p = v & 0xFFFF;
        while (p != x) {
            int gp = aload(P + p) & 0xFFFF;
            astore(P + x, gp);
            x = gp;
            p = aload(P + x) & 0xFFFF;
        }
        root = x;
        if (root != l) astore(P + l, root);
    }
    bool need = fg && (root != l);
    unsigned long long active = __ballot(need);
    const int lane = (int)(threadIdx.x & 63);
    while (active) {
        int leader = (int)__builtin_ctzll(active);
        int lroot = __shfl(root, leader);
        bool mine = need && (root == lroot);
        unsigned long long grp = __ballot(mine);
        if (lane == leader)
            atomicAdd((unsigned int*)(P + lroot), (unsigned int)__popcll(grp) << 16);
        active &= ~grp;
        need = need && !mine;
    }
}

// ---- K6: distribute — walk to root, copy full encoded word ----
__global__ void k_dist(int* parent) {
    int g = blockIdx.x * blockDim.x + threadIdx.x;
    if (g >= NPIX) return;
    int v = aload(parent + g);
    if (v == SENT_P) return;
    int l = g & (HW - 1);
    int* P = parent + (g & ~(HW - 1));
    int x = v & 0xFFFF;
    if (x == l) return;
    int w = aload(P + x);
    while ((w & 0xFFFF) != x) { x = w & 0xFFFF; w = aload(P + x); }
    astore(parent + g, w);
}

// ---- K7: finalize (element-local, vectorized) ----
__global__ void k_final(const float* __restrict__ att, const int* parent, float* out) {
    int g = blockIdx.x * blockDim.x + threadIdx.x;
    int base = g * 4;
    if (base >= NPIX) return;
    float4 v = ((const float4*)att)[g];
    int4 pv = ((const int4*)parent)[g];
    float4 y;
    {
        unsigned p = (unsigned)pv.x; float x = v.x;
        y.x = (p != (unsigned)SENT_P) ? powf(x, 1.0f / sqrtf((float)((p >> 16) + 1u))) : x;
    }
    {
        unsigned p = (unsigned)pv.y; float x = v.y;
        y.y = (p != (unsigned)SENT_P) ? powf(x, 1.0f / sqrtf((float)((p >> 16) + 1u))) : x;
    }
    {
        unsigned p = (unsigned)pv.z; float x = v.z;
        y.z = (p != (unsigned)SENT_P) ? powf(x, 1.0f / sqrtf((float)((p >> 16) + 1u))) : x;
    }
    {
        unsigned p = (unsigned)pv.w; float x = v.w;
        y.w = (p != (unsigned)SENT_P) ? powf(x, 1.0f / sqrtf((float)((p >> 16) + 1u))) : x;
    }
    ((float4*)out)[g] = y;
}

extern "C" void kernel_launch(void* const* d_in, const int* in_sizes, int n_in,
                              void* d_out, int out_size, void* d_ws, size_t ws_size,
                              hipStream_t stream) {
    const float* att = (const float*)d_in[0];
    float* out = (float*)d_out;
    int* parent = (int*)d_out;                 // labels/areas live in d_out during CC
    int* histg = (int*)d_ws;                   // 64*64 ints
    double* thr = (double*)((char*)d_ws + BATCH * 64 * sizeof(int));
    (void)in_sizes; (void)n_in; (void)out_size; (void)ws_size;

    k_clear<<<4, 1024, 0, stream>>>(histg);
    k_hist<<<dim3(8, BATCH), 256, 0, stream>>>(att, histg);
    k_thr<<<1, 64, 0, stream>>>(histg, thr);
    k_init_cc<<<dim3(TILES_PER_IMG, BATCH), 256, 0, stream>>>(att, thr, parent);
    k_bmerge<<<(BATCH * 1536 + 255) / 256, 256, 0, stream>>>(parent);
    k_flatcount<<<NPIX / 256, 256, 0, stream>>>(parent);
    k_dist<<<NPIX / 256, 256, 0, stream>>>(parent);
    k_final<<<NPIX / (256 * 4), 256, 0, stream>>>(att, parent, out);
}

// Round 16
// 218.954 us; speedup vs baseline: 80.7320x; 1.4686x over previous
//
#include <hip/hip_runtime.h>
#include <math.h>

#define BATCH 64
#define HH 256
#define WW 256
#define HW 65536            // 256*256 pixels per image
#define NPIX (BATCH * HW)   // 4194304
#define NBINS 50
#define SENT_P 0x7FFFFFFF   // background marker (never produced by area encoding)

#define TW 64
#define TH 64
#define TN (TW * TH)
#define TILES_X (WW / TW)   // 4
#define TILES_Y (HH / TH)   // 4
#define TILES_PER_IMG (TILES_X * TILES_Y)  // 16

// ws layout: int histg[64][64] (16 KB), then double thr[64] (512 B)

__device__ __forceinline__ int aload(const int* p) {
    return __hip_atomic_load(p, __ATOMIC_RELAXED, __HIP_MEMORY_SCOPE_AGENT);
}
__device__ __forceinline__ void astore(int* p, int v) {
    __hip_atomic_store(p, v, __ATOMIC_RELAXED, __HIP_MEMORY_SCOPE_AGENT);
}

// ---- K0: clear per-image histograms ----
__global__ void k_clear(int* __restrict__ histg) {
    int i = blockIdx.x * blockDim.x + threadIdx.x;
    if (i < BATCH * 64) histg[i] = 0;
}

// ---- K1: histogram, 8 blocks per image (f32 trunc binning = jnp port) ----
__global__ void k_hist(const float* __restrict__ att, int* __restrict__ histg) {
    __shared__ int h[NBINS];
    const int b = blockIdx.y, c = blockIdx.x, t = threadIdx.x;
    if (t < NBINS) h[t] = 0;
    __syncthreads();
    const float4* src = (const float4*)(att + (size_t)b * HW) + c * 2048;
    for (int i = t; i < 2048; i += 256) {
        float4 v = src[i];
        atomicAdd(&h[min((int)(v.x * 50.0f), 49)], 1);
        atomicAdd(&h[min((int)(v.y * 50.0f), 49)], 1);
        atomicAdd(&h[min((int)(v.z * 50.0f), 49)], 1);
        atomicAdd(&h[min((int)(v.w * 50.0f), 49)], 1);
    }
    __syncthreads();
    if (t < NBINS) atomicAdd(&histg[b * 64 + t], h[t]);
}

// ---- K2: per-image threshold (FLOAT64 — the R11-proven semantics) ----
__global__ void k_thr(const int* __restrict__ histg, double* __restrict__ thr) {
    int b = threadIdx.x;
    if (b >= BATCH) return;
    const int* h = histg + b * 64;
    int ind_max = 0, bv = h[0];
    for (int j = 1; j < NBINS; ++j)
        if (h[j] > bv) { bv = h[j]; ind_max = j; }     // first-occurrence argmax
    int ind_sec = 0, bv2 = -1;                          // masked[0] == -1 always
    for (int j = 1; j < NBINS; ++j) {
        int v = (j > ind_max) ? h[j] : -1;
        if (v > bv2) { bv2 = v; ind_sec = j; }          // first-occurrence
    }
    thr[b] = (double)ind_sec / 50.0;
}

// ---- LDS union-find (block-local) ----
__device__ __forceinline__ int lfind(int* lp, int x) {
    int p = lp[x];
    while (p != x) {
        int gp = lp[p];
        lp[x] = gp;           // halving
        x = gp; p = lp[x];
    }
    return x;
}
__device__ __forceinline__ void lunite(int* lp, int a, int b) {
    int ra = lfind(lp, a), rb = lfind(lp, b);
    while (ra != rb) {
        int lo = min(ra, rb), hi = max(ra, rb);
        int old = atomicMin(&lp[hi], lo);
        if (old == hi) return;
        ra = lfind(lp, lo); rb = lfind(lp, old);
    }
}

// ---- K3: fused init + tile-local CC (LDS) ----
__global__ __launch_bounds__(256)
void k_init_cc(const float* __restrict__ att, const double* __restrict__ thr,
               int* parent) {
    __shared__ int lp[TN];
    const int tile = blockIdx.x;
    const int b = blockIdx.y;
    const int t = threadIdx.x;
    const int tr0 = (tile / TILES_X) * TH;
    const int tc0 = (tile % TILES_X) * TW;
    const double tv = thr[b];
    const float* A = att + (size_t)b * HW;

    for (int i = t; i < TN / 4; i += 256) {
        int r = i >> 4, c4 = (i & 15) * 4;
        float4 v = *(const float4*)(A + (tr0 + r) * WW + tc0 + c4);
        int l = r * TW + c4;
        lp[l + 0] = ((double)v.x > tv) ? (l + 0) : SENT_P;
        lp[l + 1] = ((double)v.y > tv) ? (l + 1) : SENT_P;
        lp[l + 2] = ((double)v.z > tv) ? (l + 2) : SENT_P;
        lp[l + 3] = ((double)v.w > tv) ? (l + 3) : SENT_P;
    }
    __syncthreads();

    for (int i = t; i < TN; i += 256) {
        if (lp[i] == SENT_P) continue;
        int r = i >> 6, c = i & (TW - 1);
        if (c + 1 < TW && lp[i + 1] != SENT_P)  lunite(lp, i, i + 1);
        if (r + 1 < TH && lp[i + TW] != SENT_P) lunite(lp, i, i + TW);
    }
    __syncthreads();

    int* P = parent + (size_t)b * HW;
    for (int i = t; i < TN; i += 256) {
        int r = i >> 6, c = i & (TW - 1);
        int gidx = (tr0 + r) * WW + tc0 + c;
        int w;
        if (lp[i] == SENT_P) w = SENT_P;
        else {
            int root = lfind(lp, i);
            w = (tr0 + (root >> 6)) * WW + tc0 + (root & (TW - 1));
        }
        P[gidx] = w;                      // plain store; kernel boundary publishes
    }
}

// ---- global union-find with path halving (bmerge only) ----
__device__ __forceinline__ int findroot_h(int* P, int x) {
    int p = aload(P + x);
    while (p != x) {
        int gp = aload(P + p);
        astore(P + x, gp);
        x = gp; p = aload(P + x);
    }
    return x;
}
__device__ __forceinline__ void unite(int* P, int a, int b) {
    int ra = findroot_h(P, a);
    int rb = findroot_h(P, b);
    while (ra != rb) {
        int lo = min(ra, rb), hi = max(ra, rb);
        int old = atomicMin(&P[hi], lo);
        if (old == hi) return;
        ra = findroot_h(P, lo);
        rb = findroot_h(P, old);
    }
}

// ---- K4: boundary merge — only cross-tile edges (1536 per image) ----
__global__ void k_bmerge(int* parent) {
    int g = blockIdx.x * blockDim.x + threadIdx.x;
    if (g >= BATCH * 1536) return;
    int b = g / 1536, e = g % 1536;
    int* P = parent + (size_t)b * HW;
    int l, m;
    if (e < 768) {
        int k = e / 256, row = e & 255;
        int col = TW - 1 + TW * k;
        l = row * WW + col; m = l + 1;
    } else {
        int e2 = e - 768;
        int k = e2 / 256, col = e2 & 255;
        int row = TH - 1 + TH * k;
        l = row * WW + col; m = l + WW;
    }
    if (aload(P + l) != SENT_P && aload(P + m) != SENT_P) unite(P, l, m);
}

// ---- K5: flatten + count — PLAIN cached loads, reads-only walk, owner store ----
// Topology is FROZEN in this kernel (no linking), so L1-cached reads are safe:
// stale lines only show older valid ancestors (walk longer, still terminates;
// root-ness cannot change mid-kernel). Walk reads are masked (&0xFFFF): root
// slots' low 16 bits are stable under count atomicAdds (count <= 65535).
// NO halving stores: each thread writes ONLY ITS OWN slot with the true root,
// so at kernel end every member slot is FULLY COMPRESSED (k_dist relies on it).
__global__ void k_flatcount(int* parent) {
    int g = blockIdx.x * blockDim.x + threadIdx.x;
    int l = g & (HW - 1);
    int* P = parent + (g & ~(HW - 1));
    int v = (g < NPIX) ? P[l] : SENT_P;           // plain load
    bool fg = (v != SENT_P);
    int root = l;
    if (fg) {
        int x = v & 0xFFFF;
        while (true) {
            int w = P[x] & 0xFFFF;                // plain load (hot slots -> L1)
            if (w == x) break;
            x = w;
        }
        root = x;
        if (root != l) P[l] = root;               // owner-only compress (plain)
    }
    // wave-aggregated count: one device atomicAdd per distinct root per wave
    bool need = fg && (root != l);
    unsigned long long active = __ballot(need);
    const int lane = (int)(threadIdx.x & 63);
    while (active) {
        int leader = (int)__builtin_ctzll(active);
        int lroot = __shfl(root, leader);
        bool mine = need && (root == lroot);
        unsigned long long grp = __ballot(mine);
        if (lane == leader)
            atomicAdd((unsigned int*)(P + lroot), (unsigned int)__popcll(grp) << 16);
        active &= ~grp;
        need = need && !mine;
    }
}

// ---- K6: distribute — single-level gather (full compression guaranteed) ----
// Members read ONLY their own slot + a root slot (never written here: root
// threads return early, stores target member slots only). Race-free, plain.
__global__ void k_dist(int* parent) {
    int g = blockIdx.x * blockDim.x + threadIdx.x;
    if (g >= NPIX) return;
    int v = parent[g];                            // plain
    if (v == SENT_P) return;
    int l = g & (HW - 1);
    int r = v & 0xFFFF;
    if (r == l) return;                           // root: own slot is the word
    parent[g] = parent[(g & ~(HW - 1)) + r];      // plain gather + store
}

// ---- K7: finalize (element-local, vectorized) ----
__global__ void k_final(const float* __restrict__ att, const int* parent, float* out) {
    int g = blockIdx.x * blockDim.x + threadIdx.x;
    int base = g * 4;
    if (base >= NPIX) return;
    float4 v = ((const float4*)att)[g];
    int4 pv = ((const int4*)parent)[g];
    float4 y;
    {
        unsigned p = (unsigned)pv.x; float x = v.x;
        y.x = (p != (unsigned)SENT_P) ? powf(x, 1.0f / sqrtf((float)((p >> 16) + 1u))) : x;
    }
    {
        unsigned p = (unsigned)pv.y; float x = v.y;
        y.y = (p != (unsigned)SENT_P) ? powf(x, 1.0f / sqrtf((float)((p >> 16) + 1u))) : x;
    }
    {
        unsigned p = (unsigned)pv.z; float x = v.z;
        y.z = (p != (unsigned)SENT_P) ? powf(x, 1.0f / sqrtf((float)((p >> 16) + 1u))) : x;
    }
    {
        unsigned p = (unsigned)pv.w; float x = v.w;
        y.w = (p != (unsigned)SENT_P) ? powf(x, 1.0f / sqrtf((float)((p >> 16) + 1u))) : x;
    }
    ((float4*)out)[g] = y;
}

extern "C" void kernel_launch(void* const* d_in, const int* in_sizes, int n_in,
                              void* d_out, int out_size, void* d_ws, size_t ws_size,
                              hipStream_t stream) {
    const float* att = (const float*)d_in[0];
    float* out = (float*)d_out;
    int* parent = (int*)d_out;                 // labels/areas live in d_out during CC
    int* histg = (int*)d_ws;                   // 64*64 ints
    double* thr = (double*)((char*)d_ws + BATCH * 64 * sizeof(int));
    (void)in_sizes; (void)n_in; (void)out_size; (void)ws_size;

    k_clear<<<4, 1024, 0, stream>>>(histg);
    k_hist<<<dim3(8, BATCH), 256, 0, stream>>>(att, histg);
    k_thr<<<1, 64, 0, stream>>>(histg, thr);
    k_init_cc<<<dim3(TILES_PER_IMG, BATCH), 256, 0, stream>>>(att, thr, parent);
    k_bmerge<<<(BATCH * 1536 + 255) / 256, 256, 0, stream>>>(parent);
    k_flatcount<<<NPIX / 256, 256, 0, stream>>>(parent);
    k_dist<<<NPIX / 256, 256, 0, stream>>>(parent);
    k_final<<<NPIX / (256 * 4), 256, 0, stream>>>(att, parent, out);
}

// Round 17
// 126.957 us; speedup vs baseline: 139.2334x; 1.7246x over previous
//
#include <hip/hip_runtime.h>
#include <math.h>

#define BATCH 64
#define HH 256
#define WW 256
#define HW 65536            // 256*256 pixels per image
#define NPIX (BATCH * HW)   // 4194304
#define NBINS 50
#define SENT_P 0x7FFFFFFF   // background marker (never produced by area encoding)

#define TW 64
#define TH 64
#define TN (TW * TH)
#define TILES_X (WW / TW)   // 4
#define TILES_Y (HH / TH)   // 4
#define TILES_PER_IMG (TILES_X * TILES_Y)  // 16

// ws layout: int histg[64][64] (16 KB), then double thr[64] (512 B)

__device__ __forceinline__ int aload(const int* p) {
    return __hip_atomic_load(p, __ATOMIC_RELAXED, __HIP_MEMORY_SCOPE_AGENT);
}
__device__ __forceinline__ void astore(int* p, int v) {
    __hip_atomic_store(p, v, __ATOMIC_RELAXED, __HIP_MEMORY_SCOPE_AGENT);
}

// ---- K0: clear per-image histograms ----
__global__ void k_clear(int* __restrict__ histg) {
    int i = blockIdx.x * blockDim.x + threadIdx.x;
    if (i < BATCH * 64) histg[i] = 0;
}

// ---- K1: histogram, 8 blocks per image (f32 trunc binning = jnp port) ----
__global__ void k_hist(const float* __restrict__ att, int* __restrict__ histg) {
    __shared__ int h[NBINS];
    const int b = blockIdx.y, c = blockIdx.x, t = threadIdx.x;
    if (t < NBINS) h[t] = 0;
    __syncthreads();
    const float4* src = (const float4*)(att + (size_t)b * HW) + c * 2048;
    for (int i = t; i < 2048; i += 256) {
        float4 v = src[i];
        atomicAdd(&h[min((int)(v.x * 50.0f), 49)], 1);
        atomicAdd(&h[min((int)(v.y * 50.0f), 49)], 1);
        atomicAdd(&h[min((int)(v.z * 50.0f), 49)], 1);
        atomicAdd(&h[min((int)(v.w * 50.0f), 49)], 1);
    }
    __syncthreads();
    if (t < NBINS) atomicAdd(&histg[b * 64 + t], h[t]);
}

// ---- K2: per-image threshold (FLOAT64 — the R11-proven semantics) ----
__global__ void k_thr(const int* __restrict__ histg, double* __restrict__ thr) {
    int b = threadIdx.x;
    if (b >= BATCH) return;
    const int* h = histg + b * 64;
    int ind_max = 0, bv = h[0];
    for (int j = 1; j < NBINS; ++j)
        if (h[j] > bv) { bv = h[j]; ind_max = j; }     // first-occurrence argmax
    int ind_sec = 0, bv2 = -1;                          // masked[0] == -1 always
    for (int j = 1; j < NBINS; ++j) {
        int v = (j > ind_max) ? h[j] : -1;
        if (v > bv2) { bv2 = v; ind_sec = j; }          // first-occurrence
    }
    thr[b] = (double)ind_sec / 50.0;
}

// ---- LDS union-find (block-local) ----
__device__ __forceinline__ int lfind(int* lp, int x) {
    int p = lp[x];
    while (p != x) {
        int gp = lp[p];
        lp[x] = gp;           // halving
        x = gp; p = lp[x];
    }
    return x;
}
__device__ __forceinline__ void lunite(int* lp, int a, int b) {
    int ra = lfind(lp, a), rb = lfind(lp, b);
    while (ra != rb) {
        int lo = min(ra, rb), hi = max(ra, rb);
        int old = atomicMin(&lp[hi], lo);
        if (old == hi) return;
        ra = lfind(lp, lo); rb = lfind(lp, old);
    }
}

// ---- K3: fused init + tile-local CC + LOCAL COUNTS (LDS) ----
// Root slots leave this kernel PRE-ENCODED: groot | (localSize-1)<<16.
// Member slots leave pure (global index of tile root, depth 1).
__global__ __launch_bounds__(256)
void k_init_cc(const float* __restrict__ att, const double* __restrict__ thr,
               int* parent) {
    __shared__ int lp[TN];
    __shared__ int lcnt[TN];
    const int tile = blockIdx.x;
    const int b = blockIdx.y;
    const int t = threadIdx.x;
    const int tr0 = (tile / TILES_X) * TH;
    const int tc0 = (tile % TILES_X) * TW;
    const double tv = thr[b];
    const float* A = att + (size_t)b * HW;

    for (int i = t; i < TN / 4; i += 256) {
        int r = i >> 4, c4 = (i & 15) * 4;
        float4 v = *(const float4*)(A + (tr0 + r) * WW + tc0 + c4);
        int l = r * TW + c4;
        lp[l + 0] = ((double)v.x > tv) ? (l + 0) : SENT_P;
        lp[l + 1] = ((double)v.y > tv) ? (l + 1) : SENT_P;
        lp[l + 2] = ((double)v.z > tv) ? (l + 2) : SENT_P;
        lp[l + 3] = ((double)v.w > tv) ? (l + 3) : SENT_P;
        lcnt[l + 0] = 0; lcnt[l + 1] = 0; lcnt[l + 2] = 0; lcnt[l + 3] = 0;
    }
    __syncthreads();

    for (int i = t; i < TN; i += 256) {
        if (lp[i] == SENT_P) continue;
        int r = i >> 6, c = i & (TW - 1);
        if (c + 1 < TW && lp[i + 1] != SENT_P)  lunite(lp, i, i + 1);
        if (r + 1 < TH && lp[i + TW] != SENT_P) lunite(lp, i, i + TW);
    }
    __syncthreads();

    // local sizes: every fg pixel (root included) increments its root's count
    for (int i = t; i < TN; i += 256)
        if (lp[i] != SENT_P) atomicAdd(&lcnt[lfind(lp, i)], 1);
    __syncthreads();

    int* P = parent + (size_t)b * HW;
    for (int i = t; i < TN; i += 256) {
        int r = i >> 6, c = i & (TW - 1);
        int gidx = (tr0 + r) * WW + tc0 + c;
        int w;
        if (lp[i] == SENT_P) w = SENT_P;
        else {
            int root = lfind(lp, i);
            int groot = (tr0 + (root >> 6)) * WW + tc0 + (root & (TW - 1));
            w = (root == i) ? (groot | ((lcnt[i] - 1) << 16)) : groot;
        }
        P[gidx] = w;                      // plain store; kernel boundary publishes
    }
}

// ---- masked find with halving (bmerge only; member slots stay PURE) ----
__device__ __forceinline__ int bfind(int* P, int x) {
    while (true) {
        int p = aload(P + x) & 0xFFFF;
        if (p == x) return x;
        int gp = aload(P + p) & 0xFFFF;
        if (gp != p) astore(P + x, gp);   // halving: pure value into member slot
        x = gp;
    }
}

// ---- K4: boundary merge with COUNT-CARRYING CAS links ----
// Link root hi under lo by CAS'ing hi's EXACT root word -> lo (pure); the
// winner holds hi's count and deposits s_hi=(c+1)<<16 onto lo's current root
// via a CAS loop that only ever adds to true root words. Invariants: counts
// live only on root slots; member slots always pure; deposits ride links
// upward; final root word = root | (S_total-1)<<16, S_total <= 65536.
__device__ __forceinline__ void unite_cnt(int* P, int a, int b) {
    int ra = bfind(P, a), rb = bfind(P, b);
    while (ra != rb) {
        int lo = min(ra, rb), hi = max(ra, rb);
        int wh = aload(P + hi);
        if ((wh & 0xFFFF) != hi) {        // hi already linked; chase
            ra = bfind(P, lo); rb = bfind(P, wh & 0xFFFF);
            continue;
        }
        unsigned c = (unsigned)wh >> 16;  // s_hi - 1
        if (atomicCAS((unsigned int*)(P + hi), (unsigned)wh, (unsigned)lo) == (unsigned)wh) {
            unsigned dep = (c + 1u) << 16;      // s_hi <= 65535 when merging
            int r = lo;
            while (true) {
                int wr = aload(P + r);
                int rr = wr & 0xFFFF;
                if (rr != r) { r = rr; continue; }      // follow links
                if (atomicCAS((unsigned int*)(P + r), (unsigned)wr,
                              (unsigned)wr + dep) == (unsigned)wr) break;
            }
            return;
        }
        ra = bfind(P, lo); rb = bfind(P, hi);
    }
}

__global__ void k_bmerge(int* parent) {
    int g = blockIdx.x * blockDim.x + threadIdx.x;
    if (g >= BATCH * 1536) return;
    int b = g / 1536, e = g % 1536;
    int* P = parent + (size_t)b * HW;
    int l, m;
    if (e < 768) {          // vertical edges: col in {63,127,191} -> col+1
        int k = e / 256, row = e & 255;
        int col = TW - 1 + TW * k;
        l = row * WW + col; m = l + 1;
    } else {                // horizontal edges: row in {63,127,191} -> row+1
        int e2 = e - 768;
        int k = e2 / 256, col = e2 & 255;
        int row = TH - 1 + TH * k;
        l = row * WW + col; m = l + WW;
    }
    if (aload(P + l) != SENT_P && aload(P + m) != SENT_P) unite_cnt(P, l, m);
}

// ---- K5: distribute — masked walk to root, copy encoded word (4 px/thread) ----
// Topology + counts FROZEN after bmerge -> plain cached loads are safe.
// Walk depth ~2 (member -> tile root -> final root). Encoded words written
// into member slots only fast-forward other walkers (low bits = root index).
__global__ void k_dist(int* parent) {
    int g4 = blockIdx.x * blockDim.x + threadIdx.x;
    int base = g4 * 4;
    if (base >= NPIX) return;
    int* P = parent + (base & ~(HW - 1));
    int l0 = base & (HW - 1);
    int4 v = ((const int4*)parent)[g4];
    int vv[4] = {v.x, v.y, v.z, v.w};
    bool changed = false;
#pragma unroll
    for (int j = 0; j < 4; ++j) {
        int w = vv[j];
        if (w == SENT_P) continue;
        int l = l0 + j;
        int x = w & 0xFFFF;
        if (x == l) continue;                 // root: own slot already the word
        int wx = P[x];                        // plain load (hot slots -> L1)
        while ((wx & 0xFFFF) != x) { x = wx & 0xFFFF; wx = P[x]; }
        vv[j] = wx;
        changed = true;
    }
    if (changed)
        ((int4*)parent)[g4] = make_int4(vv[0], vv[1], vv[2], vv[3]);
}

// ---- K6: finalize (element-local, vectorized) ----
__global__ void k_final(const float* __restrict__ att, const int* parent, float* out) {
    int g = blockIdx.x * blockDim.x + threadIdx.x;
    int base = g * 4;
    if (base >= NPIX) return;
    float4 v = ((const float4*)att)[g];
    int4 pv = ((const int4*)parent)[g];
    float4 y;
    {
        unsigned p = (unsigned)pv.x; float x = v.x;
        y.x = (p != (unsigned)SENT_P) ? powf(x, 1.0f / sqrtf((float)((p >> 16) + 1u))) : x;
    }
    {
        unsigned p = (unsigned)pv.y; float x = v.y;
        y.y = (p != (unsigned)SENT_P) ? powf(x, 1.0f / sqrtf((float)((p >> 16) + 1u))) : x;
    }
    {
        unsigned p = (unsigned)pv.z; float x = v.z;
        y.z = (p != (unsigned)SENT_P) ? powf(x, 1.0f / sqrtf((float)((p >> 16) + 1u))) : x;
    }
    {
        unsigned p = (unsigned)pv.w; float x = v.w;
        y.w = (p != (unsigned)SENT_P) ? powf(x, 1.0f / sqrtf((float)((p >> 16) + 1u))) : x;
    }
    ((float4*)out)[g] = y;
}

extern "C" void kernel_launch(void* const* d_in, const int* in_sizes, int n_in,
                              void* d_out, int out_size, void* d_ws, size_t ws_size,
                              hipStream_t stream) {
    const float* att = (const float*)d_in[0];
    float* out = (float*)d_out;
    int* parent = (int*)d_out;                 // labels/areas live in d_out during CC
    int* histg = (int*)d_ws;                   // 64*64 ints
    double* thr = (double*)((char*)d_ws + BATCH * 64 * sizeof(int));
    (void)in_sizes; (void)n_in; (void)out_size; (void)ws_size;

    k_clear<<<4, 1024, 0, stream>>>(histg);
    k_hist<<<dim3(8, BATCH), 256, 0, stream>>>(att, histg);
    k_thr<<<1, 64, 0, stream>>>(histg, thr);
    k_init_cc<<<dim3(TILES_PER_IMG, BATCH), 256, 0, stream>>>(att, thr, parent);
    k_bmerge<<<(BATCH * 1536 + 255) / 256, 256, 0, stream>>>(parent);
    k_dist<<<NPIX / (256 * 4), 256, 0, stream>>>(parent);
    k_final<<<NPIX / (256 * 4), 256, 0, stream>>>(att, parent, out);
}

// Round 18
// 100.705 us; speedup vs baseline: 175.5286x; 1.2607x over previous
//
#include <hip/hip_runtime.h>
#include <math.h>

#define BATCH 64
#define HH 256
#define WW 256
#define HW 65536            // 256*256 pixels per image
#define NPIX (BATCH * HW)   // 4194304
#define NBINS 50
#define SENT_P 0x7FFFFFFF   // background marker (never produced by area encoding)

#define TW 64
#define TH 64
#define TN (TW * TH)
#define TILES_X (WW / TW)   // 4
#define TILES_Y (HH / TH)   // 4
#define TILES_PER_IMG (TILES_X * TILES_Y)  // 16

__device__ __forceinline__ int aload(const int* p) {
    return __hip_atomic_load(p, __ATOMIC_RELAXED, __HIP_MEMORY_SCOPE_AGENT);
}
__device__ __forceinline__ void astore(int* p, int v) {
    __hip_atomic_store(p, v, __ATOMIC_RELAXED, __HIP_MEMORY_SCOPE_AGENT);
}

// run-start of the run containing column c (bit c of mask must be 1)
__device__ __forceinline__ int runstart64(unsigned long long m, int c) {
    unsigned long long sh = (~m) << (63 - c);
    return sh ? (c - __clzll(sh) + 1) : 0;
}
// run length starting at run-start column c
__device__ __forceinline__ int runlen64(unsigned long long m, int c) {
    unsigned long long sh = ~(m >> c);
    return sh ? (__ffsll(sh) - 1) : 64;
}

// ---- K1: histogram partials, 8 blocks per image (f32 trunc binning) ----
// Writes block-private partial hist -> no zeroing kernel needed.
__global__ void k_hist(const float* __restrict__ att, int* __restrict__ histp) {
    __shared__ int h[NBINS];
    const int b = blockIdx.y, c = blockIdx.x, t = threadIdx.x;
    if (t < NBINS) h[t] = 0;
    __syncthreads();
    const float4* src = (const float4*)(att + (size_t)b * HW) + c * 2048;
    for (int i = t; i < 2048; i += 256) {
        float4 v = src[i];
        atomicAdd(&h[min((int)(v.x * 50.0f), 49)], 1);
        atomicAdd(&h[min((int)(v.y * 50.0f), 49)], 1);
        atomicAdd(&h[min((int)(v.z * 50.0f), 49)], 1);
        atomicAdd(&h[min((int)(v.w * 50.0f), 49)], 1);
    }
    __syncthreads();
    if (t < NBINS) histp[(b * 8 + c) * 64 + t] = h[t];
}

// ---- K2: per-image threshold (FLOAT64 — the R11-proven semantics) ----
__global__ void k_thr(const int* __restrict__ histp, double* __restrict__ thr) {
    int b = threadIdx.x;
    if (b >= BATCH) return;
    int h[NBINS];
#pragma unroll
    for (int j = 0; j < NBINS; ++j) {
        int s = 0;
        for (int c = 0; c < 8; ++c) s += histp[(b * 8 + c) * 64 + j];
        h[j] = s;
    }
    int ind_max = 0, bv = h[0];
    for (int j = 1; j < NBINS; ++j)
        if (h[j] > bv) { bv = h[j]; ind_max = j; }     // first-occurrence argmax
    int ind_sec = 0, bv2 = -1;                          // masked[0] == -1 always
    for (int j = 1; j < NBINS; ++j) {
        int v = (j > ind_max) ? h[j] : -1;
        if (v > bv2) { bv2 = v; ind_sec = j; }          // first-occurrence
    }
    thr[b] = (double)ind_sec / 50.0;
}

// ---- LDS union-find over RUN-START nodes (pure values during union) ----
__device__ __forceinline__ int lfind(int* lp, int x) {
    int p = lp[x];
    while (p != x) {
        int gp = lp[p];
        if (gp != p) lp[x] = gp;     // halving
        x = gp; p = lp[x];
    }
    return x;
}
__device__ __forceinline__ void lunite(int* lp, int a, int b) {
    int ra = lfind(lp, a), rb = lfind(lp, b);
    while (ra != rb) {
        int lo = min(ra, rb), hi = max(ra, rb);
        int old = atomicMin(&lp[hi], lo);
        if (old == hi) return;
        ra = lfind(lp, lo); rb = lfind(lp, old);
    }
}
// masked find (post-union: root slots carry counts in high 16 bits)
__device__ __forceinline__ int lfindm(int* lp, int x) {
    while (true) {
        int p = lp[x] & 0xFFFF;
        if (p == x) return x;
        int gp = lp[p] & 0xFFFF;
        if (gp != p) lp[x] = gp;     // halving writes pure values, non-root only
        x = gp;
    }
}

// ---- K3: fused init + run-based tile CC + local counts ----
// Wave per row (64 lanes = 64 cols): fg mask via ballot; union-find nodes are
// RUN STARTS only; vertical unions deduped per overlap segment; run lengths
// deposited into lp[root] high bits. Root slots leave PRE-ENCODED:
// groot | (size-1)<<16; member slots leave pure (global idx of tile root).
__global__ __launch_bounds__(256)
void k_init_cc(const float* __restrict__ att, const double* __restrict__ thr,
               int* parent) {
    __shared__ int lp[TN];
    __shared__ unsigned long long msk[TH];
    const int tile = blockIdx.x;
    const int b = blockIdx.y;
    const int t = threadIdx.x;
    const int wv = t >> 6, ln = t & 63;
    const int tr0 = (tile / TILES_X) * TH;
    const int tc0 = (tile % TILES_X) * TW;
    const double tv = thr[b];
    const float* A = att + (size_t)b * HW;

    // Phase 1: masks + lp init at run starts
    for (int k = 0; k < 16; ++k) {
        int r = wv + 4 * k;
        float x = A[(tr0 + r) * WW + tc0 + ln];
        bool fg = (double)x > tv;
        unsigned long long m = __ballot(fg);
        if (ln == 0) msk[r] = m;
        if (fg && (ln == 0 || !((m >> (ln - 1)) & 1ull)))
            lp[r * TW + ln] = r * TW + ln;
    }
    __syncthreads();

    // Phase 2: vertical unions, one per overlap segment
    for (int k = 0; k < 16; ++k) {
        int r = wv + 4 * k;
        if (r >= TH - 1) continue;
        unsigned long long m0 = msk[r], m1 = msk[r + 1];
        unsigned long long ov = m0 & m1;
        if (((ov >> ln) & 1ull) && (ln == 0 || !((ov >> (ln - 1)) & 1ull)))
            lunite(lp, r * TW + runstart64(m0, ln),
                       (r + 1) * TW + runstart64(m1, ln));
    }
    __syncthreads();

    // Phase 3: deposit run lengths at roots (masked finds from here on)
    for (int k = 0; k < 16; ++k) {
        int r = wv + 4 * k;
        unsigned long long m = msk[r];
        if (((m >> ln) & 1ull) && (ln == 0 || !((m >> (ln - 1)) & 1ull))) {
            int L = runlen64(m, ln);
            int root = lfindm(lp, r * TW + ln);
            atomicAdd(&lp[root], L << 16);
        }
    }
    __syncthreads();

    // Phase 4: write global parent, 4 px per iteration (int4)
    int* P = parent + (size_t)b * HW;
    for (int i = t; i < TN / 4; i += 256) {
        int r = i >> 4, c4 = (i & 15) * 4;
        unsigned long long m = msk[r];
        int w[4];
#pragma unroll
        for (int j = 0; j < 4; ++j) {
            int c = c4 + j, l = r * TW + c;
            if (!((m >> c) & 1ull)) { w[j] = SENT_P; continue; }
            int node = r * TW + runstart64(m, c);
            int root = lfindm(lp, node);
            int groot = (tr0 + (root >> 6)) * WW + tc0 + (root & (TW - 1));
            w[j] = (l == root) ? (groot | (((lp[root] >> 16) - 1) << 16)) : groot;
        }
        *(int4*)(P + (tr0 + r) * WW + tc0 + c4) = make_int4(w[0], w[1], w[2], w[3]);
    }
}

// ---- global masked find with halving (member slots stay pure) ----
__device__ __forceinline__ int bfind(int* P, int x) {
    while (true) {
        int p = aload(P + x) & 0xFFFF;
        if (p == x) return x;
        int gp = aload(P + p) & 0xFFFF;
        if (gp != p) astore(P + x, gp);
        x = gp;
    }
}

// ---- K4: boundary merge with count-carrying CAS links (R17-proven) ----
__device__ __forceinline__ void unite_cnt(int* P, int a, int b) {
    int ra = bfind(P, a), rb = bfind(P, b);
    while (ra != rb) {
        int lo = min(ra, rb), hi = max(ra, rb);
        int wh = aload(P + hi);
        if ((wh & 0xFFFF) != hi) {
            ra = bfind(P, lo); rb = bfind(P, wh & 0xFFFF);
            continue;
        }
        unsigned c = (unsigned)wh >> 16;
        if (atomicCAS((unsigned int*)(P + hi), (unsigned)wh, (unsigned)lo) == (unsigned)wh) {
            unsigned dep = (c + 1u) << 16;
            int r = lo;
            while (true) {
                int wr = aload(P + r);
                int rr = wr & 0xFFFF;
                if (rr != r) { r = rr; continue; }
                if (atomicCAS((unsigned int*)(P + r), (unsigned)wr,
                              (unsigned)wr + dep) == (unsigned)wr) break;
            }
            return;
        }
        ra = bfind(P, lo); rb = bfind(P, hi);
    }
}

__global__ void k_bmerge(int* parent) {
    int g = blockIdx.x * blockDim.x + threadIdx.x;
    if (g >= BATCH * 1536) return;
    int b = g / 1536, e = g % 1536;
    int* P = parent + (size_t)b * HW;
    int l, m;
    if (e < 768) {
        int k = e / 256, row = e & 255;
        l = row * WW + (TW - 1 + TW * k); m = l + 1;
    } else {
        int e2 = e - 768;
        int k = e2 / 256, col = e2 & 255;
        l = (TH - 1 + TH * k) * WW + col; m = l + WW;
    }
    if (aload(P + l) != SENT_P && aload(P + m) != SENT_P) unite_cnt(P, l, m);
}

// ---- K5 (fallback only): distribute encoded root word into member slots ----
__global__ void k_dist(int* parent) {
    int g4 = blockIdx.x * blockDim.x + threadIdx.x;
    int base = g4 * 4;
    if (base >= NPIX) return;
    int* P = parent + (base & ~(HW - 1));
    int l0 = base & (HW - 1);
    int4 v = ((const int4*)parent)[g4];
    int vv[4] = {v.x, v.y, v.z, v.w};
    bool changed = false;
#pragma unroll
    for (int j = 0; j < 4; ++j) {
        int w = vv[j];
        if (w == SENT_P) continue;
        int x = w & 0xFFFF;
        if (x == l0 + j) continue;
        int wx = P[x];
        while ((wx & 0xFFFF) != x) { x = wx & 0xFFFF; wx = P[x]; }
        vv[j] = wx; changed = true;
    }
    if (changed) ((int4*)parent)[g4] = make_int4(vv[0], vv[1], vv[2], vv[3]);
}

// ---- K6: finalize — walks frozen parent (plain cached) when walk!=0 ----
__global__ void k_final(const float* __restrict__ att, const int* parent,
                        float* out, int walk) {
    int g = blockIdx.x * blockDim.x + threadIdx.x;
    int base = g * 4;
    if (base >= NPIX) return;
    const int* P = parent + (base & ~(HW - 1));
    int l0 = base & (HW - 1);
    float4 v = ((const float4*)att)[g];
    int4 pv = ((const int4*)parent)[g];     // own slots (read before any alias write)
    int vv[4] = {pv.x, pv.y, pv.z, pv.w};
    float xs[4] = {v.x, v.y, v.z, v.w};
    float ys[4];
#pragma unroll
    for (int j = 0; j < 4; ++j) {
        float x = xs[j];
        int w = vv[j];
        if (w == SENT_P) { ys[j] = x; continue; }
        unsigned enc = (unsigned)w;
        if (walk) {
            int xi = w & 0xFFFF;
            if (xi != l0 + j) {             // member: walk to root (depth ~1-2)
                int wx = P[xi];
                while ((wx & 0xFFFF) != xi) { xi = wx & 0xFFFF; wx = P[xi]; }
                enc = (unsigned)wx;
            }
        }
        float a = (float)((enc >> 16) + 1u);
        ys[j] = powf(x, 1.0f / sqrtf(a));
    }
    ((float4*)out)[g] = make_float4(ys[0], ys[1], ys[2], ys[3]);
}

extern "C" void kernel_launch(void* const* d_in, const int* in_sizes, int n_in,
                              void* d_out, int out_size, void* d_ws, size_t ws_size,
                              hipStream_t stream) {
    const float* att = (const float*)d_in[0];
    float* out = (float*)d_out;
    (void)in_sizes; (void)n_in; (void)out_size;

    const size_t PAR_BYTES = (size_t)NPIX * 4;
    const size_t HIST_BYTES = (size_t)BATCH * 8 * 64 * 4;   // 131072
    bool ws_big = ws_size >= PAR_BYTES + HIST_BYTES + 512;

    int* parent;
    int* histp;
    double* thr;
    if (ws_big) {           // main path: parent in ws, final walks, no dist
        parent = (int*)d_ws;
        histp = (int*)((char*)d_ws + PAR_BYTES);
        thr = (double*)((char*)d_ws + PAR_BYTES + HIST_BYTES);
    } else {                // fallback: parent aliases d_out (R17 path)
        parent = (int*)d_out;
        histp = (int*)d_ws;
        thr = (double*)((char*)d_ws + HIST_BYTES);
    }

    k_hist<<<dim3(8, BATCH), 256, 0, stream>>>(att, histp);
    k_thr<<<1, 64, 0, stream>>>(histp, thr);
    k_init_cc<<<dim3(TILES_PER_IMG, BATCH), 256, 0, stream>>>(att, thr, parent);
    k_bmerge<<<(BATCH * 1536 + 255) / 256, 256, 0, stream>>>(parent);
    if (!ws_big)
        k_dist<<<NPIX / (256 * 4), 256, 0, stream>>>(parent);
    k_final<<<NPIX / (256 * 4), 256, 0, stream>>>(att, parent, out, ws_big ? 1 : 0);
}

// Round 19
// 96.459 us; speedup vs baseline: 183.2540x; 1.0440x over previous
//
#include <hip/hip_runtime.h>
#include <math.h>

#define BATCH 64
#define HH 256
#define WW 256
#define HW 65536            // 256*256 pixels per image
#define NPIX (BATCH * HW)   // 4194304
#define NBINS 50
#define SENT_P 0x7FFFFFFF   // background marker (never produced by area encoding)

#define TW 64
#define TH 64
#define TN (TW * TH)
#define TILES_X (WW / TW)   // 4
#define TILES_Y (HH / TH)   // 4
#define TILES_PER_IMG (TILES_X * TILES_Y)  // 16

__device__ __forceinline__ int aload(const int* p) {
    return __hip_atomic_load(p, __ATOMIC_RELAXED, __HIP_MEMORY_SCOPE_AGENT);
}
__device__ __forceinline__ void astore(int* p, int v) {
    __hip_atomic_store(p, v, __ATOMIC_RELAXED, __HIP_MEMORY_SCOPE_AGENT);
}

// run-start of the run containing column c (bit c of mask must be 1)
__device__ __forceinline__ int runstart64(unsigned long long m, int c) {
    unsigned long long sh = (~m) << (63 - c);
    return sh ? (c - __clzll(sh) + 1) : 0;
}
// run length starting at run-start column c
__device__ __forceinline__ int runlen64(unsigned long long m, int c) {
    unsigned long long sh = ~(m >> c);
    return sh ? (__ffsll(sh) - 1) : 64;
}

// wave-wide argmax: max val, tie -> min idx (== np first-occurrence argmax)
__device__ __forceinline__ void wave_argmax(int& bv, int& bi) {
#pragma unroll
    for (int off = 32; off > 0; off >>= 1) {
        int ov = __shfl_xor(bv, off);
        int oi = __shfl_xor(bi, off);
        if (ov > bv || (ov == bv && oi < bi)) { bv = ov; bi = oi; }
    }
}

// ---- K1: histogram partials, 8 blocks per image (f32 trunc binning) ----
__global__ void k_hist(const float* __restrict__ att, int* __restrict__ histp) {
    __shared__ int h[NBINS];
    const int b = blockIdx.y, c = blockIdx.x, t = threadIdx.x;
    if (t < NBINS) h[t] = 0;
    __syncthreads();
    const float4* src = (const float4*)(att + (size_t)b * HW) + c * 2048;
    for (int i = t; i < 2048; i += 256) {
        float4 v = src[i];
        atomicAdd(&h[min((int)(v.x * 50.0f), 49)], 1);
        atomicAdd(&h[min((int)(v.y * 50.0f), 49)], 1);
        atomicAdd(&h[min((int)(v.z * 50.0f), 49)], 1);
        atomicAdd(&h[min((int)(v.w * 50.0f), 49)], 1);
    }
    __syncthreads();
    if (t < NBINS) histp[(b * 8 + c) * 64 + t] = h[t];
}

// ---- LDS union-find over RUN-START nodes (pure values during union) ----
__device__ __forceinline__ int lfind(int* lp, int x) {
    int p = lp[x];
    while (p != x) {
        int gp = lp[p];
        if (gp != p) lp[x] = gp;     // halving
        x = gp; p = lp[x];
    }
    return x;
}
__device__ __forceinline__ void lunite(int* lp, int a, int b) {
    int ra = lfind(lp, a), rb = lfind(lp, b);
    while (ra != rb) {
        int lo = min(ra, rb), hi = max(ra, rb);
        int old = atomicMin(&lp[hi], lo);
        if (old == hi) return;
        ra = lfind(lp, lo); rb = lfind(lp, old);
    }
}
// masked find (post-union: root slots carry counts in high 16 bits)
__device__ __forceinline__ int lfindm(int* lp, int x) {
    while (true) {
        int p = lp[x] & 0xFFFF;
        if (p == x) return x;
        int gp = lp[p] & 0xFFFF;
        if (gp != p) lp[x] = gp;     // halving writes pure values, non-root only
        x = gp;
    }
}

// ---- K2: fused THRESHOLD + init + run-based tile CC + local counts ----
// Threshold (R11-proven f64 semantics) computed per-wave from histp partials:
// 50 lanes sum 8 partials each; two wave argmax reductions (first-occurrence,
// incl. the all-(-1) -> ind_sec=0 edge case). No separate k_thr kernel.
__global__ __launch_bounds__(256)
void k_init_cc(const float* __restrict__ att, const int* __restrict__ histp,
               int* parent) {
    __shared__ int lp[TN];
    __shared__ unsigned long long msk[TH];
    const int tile = blockIdx.x;
    const int b = blockIdx.y;
    const int t = threadIdx.x;
    const int wv = t >> 6, ln = t & 63;
    const int tr0 = (tile / TILES_X) * TH;
    const int tc0 = (tile % TILES_X) * TW;
    const float* A = att + (size_t)b * HW;

    // Phase 0: per-wave inline threshold
    int h_ln = 0;
    if (ln < NBINS)
        for (int c = 0; c < 8; ++c) h_ln += histp[(b * 8 + c) * 64 + ln];
    int bv = (ln < NBINS) ? h_ln : -1, bi = ln;
    wave_argmax(bv, bi);
    const int ind_max = bi;                        // first-occurrence argmax
    int bv2 = (ln < NBINS && ln > ind_max) ? h_ln : -1, bi2 = ln;
    wave_argmax(bv2, bi2);                         // masked argmax; all -1 -> 0
    const double tv = (double)bi2 / 50.0;          // FLOAT64 threshold

    // Phase 1: masks + lp init at run starts
    for (int k = 0; k < 16; ++k) {
        int r = wv + 4 * k;
        float x = A[(tr0 + r) * WW + tc0 + ln];
        bool fg = (double)x > tv;
        unsigned long long m = __ballot(fg);
        if (ln == 0) msk[r] = m;
        if (fg && (ln == 0 || !((m >> (ln - 1)) & 1ull)))
            lp[r * TW + ln] = r * TW + ln;
    }
    __syncthreads();

    // Phase 2: vertical unions, one per overlap segment
    for (int k = 0; k < 16; ++k) {
        int r = wv + 4 * k;
        if (r >= TH - 1) continue;
        unsigned long long m0 = msk[r], m1 = msk[r + 1];
        unsigned long long ov = m0 & m1;
        if (((ov >> ln) & 1ull) && (ln == 0 || !((ov >> (ln - 1)) & 1ull)))
            lunite(lp, r * TW + runstart64(m0, ln),
                       (r + 1) * TW + runstart64(m1, ln));
    }
    __syncthreads();

    // Phase 3: deposit run lengths at roots (masked finds from here on)
    for (int k = 0; k < 16; ++k) {
        int r = wv + 4 * k;
        unsigned long long m = msk[r];
        if (((m >> ln) & 1ull) && (ln == 0 || !((m >> (ln - 1)) & 1ull))) {
            int L = runlen64(m, ln);
            int root = lfindm(lp, r * TW + ln);
            atomicAdd(&lp[root], L << 16);
        }
    }
    __syncthreads();

    // Phase 4: write global parent, 4 px per iteration (int4)
    int* P = parent + (size_t)b * HW;
    for (int i = t; i < TN / 4; i += 256) {
        int r = i >> 4, c4 = (i & 15) * 4;
        unsigned long long m = msk[r];
        int w[4];
#pragma unroll
        for (int j = 0; j < 4; ++j) {
            int c = c4 + j, l = r * TW + c;
            if (!((m >> c) & 1ull)) { w[j] = SENT_P; continue; }
            int node = r * TW + runstart64(m, c);
            int root = lfindm(lp, node);
            int groot = (tr0 + (root >> 6)) * WW + tc0 + (root & (TW - 1));
            w[j] = (l == root) ? (groot | (((lp[root] >> 16) - 1) << 16)) : groot;
        }
        *(int4*)(P + (tr0 + r) * WW + tc0 + c4) = make_int4(w[0], w[1], w[2], w[3]);
    }
}

// ---- global masked find with halving (member slots stay pure) ----
__device__ __forceinline__ int bfind(int* P, int x) {
    while (true) {
        int p = aload(P + x) & 0xFFFF;
        if (p == x) return x;
        int gp = aload(P + p) & 0xFFFF;
        if (gp != p) astore(P + x, gp);
        x = gp;
    }
}

// ---- K3: boundary merge with count-carrying CAS links (R17-proven) ----
__device__ __forceinline__ void unite_cnt(int* P, int a, int b) {
    int ra = bfind(P, a), rb = bfind(P, b);
    while (ra != rb) {
        int lo = min(ra, rb), hi = max(ra, rb);
        int wh = aload(P + hi);
        if ((wh & 0xFFFF) != hi) {
            ra = bfind(P, lo); rb = bfind(P, wh & 0xFFFF);
            continue;
        }
        unsigned c = (unsigned)wh >> 16;
        if (atomicCAS((unsigned int*)(P + hi), (unsigned)wh, (unsigned)lo) == (unsigned)wh) {
            unsigned dep = (c + 1u) << 16;
            int r = lo;
            while (true) {
                int wr = aload(P + r);
                int rr = wr & 0xFFFF;
                if (rr != r) { r = rr; continue; }
                if (atomicCAS((unsigned int*)(P + r), (unsigned)wr,
                              (unsigned)wr + dep) == (unsigned)wr) break;
            }
            return;
        }
        ra = bfind(P, lo); rb = bfind(P, hi);
    }
}

__global__ void k_bmerge(int* parent) {
    int g = blockIdx.x * blockDim.x + threadIdx.x;
    if (g >= BATCH * 1536) return;
    int b = g / 1536, e = g % 1536;
    int* P = parent + (size_t)b * HW;
    int l, m;
    if (e < 768) {
        int k = e / 256, row = e & 255;
        l = row * WW + (TW - 1 + TW * k); m = l + 1;
    } else {
        int e2 = e - 768;
        int k = e2 / 256, col = e2 & 255;
        l = (TH - 1 + TH * k) * WW + col; m = l + WW;
    }
    if (aload(P + l) != SENT_P && aload(P + m) != SENT_P) unite_cnt(P, l, m);
}

// ---- K4 (fallback only): distribute encoded root word into member slots ----
__global__ void k_dist(int* parent) {
    int g4 = blockIdx.x * blockDim.x + threadIdx.x;
    int base = g4 * 4;
    if (base >= NPIX) return;
    int* P = parent + (base & ~(HW - 1));
    int l0 = base & (HW - 1);
    int4 v = ((const int4*)parent)[g4];
    int vv[4] = {v.x, v.y, v.z, v.w};
    bool changed = false;
#pragma unroll
    for (int j = 0; j < 4; ++j) {
        int w = vv[j];
        if (w == SENT_P) continue;
        int x = w & 0xFFFF;
        if (x == l0 + j) continue;
        int wx = P[x];
        while ((wx & 0xFFFF) != x) { x = wx & 0xFFFF; wx = P[x]; }
        vv[j] = wx; changed = true;
    }
    if (changed) ((int4*)parent)[g4] = make_int4(vv[0], vv[1], vv[2], vv[3]);
}

// ---- K5: finalize — walks frozen parent (plain cached) when walk!=0 ----
__global__ void k_final(const float* __restrict__ att, const int* parent,
                        float* out, int walk) {
    int g = blockIdx.x * blockDim.x + threadIdx.x;
    int base = g * 4;
    if (base >= NPIX) return;
    const int* P = parent + (base & ~(HW - 1));
    int l0 = base & (HW - 1);
    float4 v = ((const float4*)att)[g];
    int4 pv = ((const int4*)parent)[g];
    int vv[4] = {pv.x, pv.y, pv.z, pv.w};
    float xs[4] = {v.x, v.y, v.z, v.w};
    float ys[4];
#pragma unroll
    for (int j = 0; j < 4; ++j) {
        float x = xs[j];
        int w = vv[j];
        if (w == SENT_P) { ys[j] = x; continue; }
        unsigned enc = (unsigned)w;
        if (walk) {
            int xi = w & 0xFFFF;
            if (xi != l0 + j) {             // member: walk to root (depth ~1-2)
                int wx = P[xi];
                while ((wx & 0xFFFF) != xi) { xi = wx & 0xFFFF; wx = P[xi]; }
                enc = (unsigned)wx;
            }
        }
        float a = (float)((enc >> 16) + 1u);
        ys[j] = powf(x, 1.0f / sqrtf(a));
    }
    ((float4*)out)[g] = make_float4(ys[0], ys[1], ys[2], ys[3]);
}

extern "C" void kernel_launch(void* const* d_in, const int* in_sizes, int n_in,
                              void* d_out, int out_size, void* d_ws, size_t ws_size,
                              hipStream_t stream) {
    const float* att = (const float*)d_in[0];
    float* out = (float*)d_out;
    (void)in_sizes; (void)n_in; (void)out_size;

    const size_t PAR_BYTES = (size_t)NPIX * 4;
    const size_t HIST_BYTES = (size_t)BATCH * 8 * 64 * 4;   // 131072
    bool ws_big = ws_size >= PAR_BYTES + HIST_BYTES + 512;

    int* parent;
    int* histp;
    if (ws_big) {           // main path: parent in ws, final walks, no dist
        parent = (int*)d_ws;
        histp = (int*)((char*)d_ws + PAR_BYTES);
    } else {                // fallback: parent aliases d_out
        parent = (int*)d_out;
        histp = (int*)d_ws;
    }

    k_hist<<<dim3(8, BATCH), 256, 0, stream>>>(att, histp);
    k_init_cc<<<dim3(TILES_PER_IMG, BATCH), 256, 0, stream>>>(att, histp, parent);
    k_bmerge<<<(BATCH * 1536 + 255) / 256, 256, 0, stream>>>(parent);
    if (!ws_big)
        k_dist<<<NPIX / (256 * 4), 256, 0, stream>>>(parent);
    k_final<<<NPIX / (256 * 4), 256, 0, stream>>>(att, parent, out, ws_big ? 1 : 0);
}